// Round 18
// baseline (173.621 us; speedup 1.0000x reference)
//
#include <hip/hip_runtime.h>

// FP8 MLP, fully fused:  out = q(relu(q(x)@q(w1)^T)) @ q(w2)^T
// R18 = R17 (R12 + conflict-free involution; 171us, 52 VGPR, no spill)
// + WAVE PHASE ROTATION: waves 4..7 traverse the chunk's 13 K-tiles starting
// at ks=7 (kse=(ks+START)%13, compile-time via 2 macro instantiations).
// Sum over ks is order-independent => correctness unchanged. Mechanism: at any
// instant ~half the waves per SIMD are in the ds_read phase and half in the
// MFMA phase, so the LDS pipe and matrix pipe overlap instead of alternating
// (R17 post-mortem: observed per-t ~= MFMA + LDS serial sum, lockstep convoy).

typedef float f32x4 __attribute__((ext_vector_type(4)));
typedef float f32x16 __attribute__((ext_vector_type(16)));

#define DIN 784
#define KP  832          // 13 * 64 (zero-padded K)
#define DH  4096
#define NKS 13
#define NCH 16
#define CHUNK 256
#define MROWS 64

__device__ __forceinline__ unsigned long long q8(float4 a, float4 b) {
  int lo = __builtin_amdgcn_cvt_pk_fp8_f32(a.x, a.y, 0, false);
  lo     = __builtin_amdgcn_cvt_pk_fp8_f32(a.z, a.w, lo, true);
  int hi = __builtin_amdgcn_cvt_pk_fp8_f32(b.x, b.y, 0, false);
  hi     = __builtin_amdgcn_cvt_pk_fp8_f32(b.z, b.w, hi, true);
  return (unsigned long long)(unsigned)lo |
         ((unsigned long long)(unsigned)hi << 32);
}

__device__ __forceinline__ f32x16 zero16() { f32x16 z = {}; return z; }

// ---- w1 quantize: f32 [4096][784] -> fp8, wave-coalesced blocked layout ----
// 16KB block (nch*13+ks). Within: slice=(n>>5)&7 (2KB = 32 dh rows),
// tq=q&1 (1KB = k-half), lane 16B = ((q>>1)*32 + (n&31))*16.
// 16B content: va=q8(w1[n][ks*64+(q&1)*32+(q>>1)*8..+8]), vb = same +16.

__global__ __launch_bounds__(256) void quant_w1_k(const float* __restrict__ w1,
                                                  unsigned char* __restrict__ w1qb) {
  int idx = blockIdx.x * 256 + threadIdx.x;       // 4096 n * 52 groups
  int n = idx / 52, g = idx % 52;
  int ks = g >> 2, q = g & 3;
  int kA = ks * 64 + (q & 1) * 32 + (q >> 1) * 8;
  int kB = kA + 16;
  const float* r = w1 + (size_t)n * DIN;
  unsigned long long va = 0ull, vb = 0ull;
  if (kA < DIN) va = q8(*(const float4*)(r + kA), *(const float4*)(r + kA + 4));
  if (kB < DIN) vb = q8(*(const float4*)(r + kB), *(const float4*)(r + kB + 4));
  ulonglong2 v; v.x = va; v.y = vb;
  size_t off = ((size_t)((n >> 8) * NKS + ks) << 14) + ((n >> 5) & 7) * 2048 +
               (q & 1) * 1024 + ((q >> 1) * 32 + (n & 31)) * 16;
  *(ulonglong2*)(w1qb + off) = v;
}

__global__ __launch_bounds__(256) void quant_w2_k(const float* __restrict__ w2,
                                                  unsigned char* __restrict__ w2q) {
  int idx = blockIdx.x * 256 + threadIdx.x;       // 16 rows * 256 chunks(16B)
  int r = idx >> 8, c = idx & 255;
  ulonglong2 v; v.x = 0ull; v.y = 0ull;
  if (r < 10) {
    const float* p = w2 + (size_t)r * DH + c * 16;
    v.x = q8(*(const float4*)(p), *(const float4*)(p + 4));
    v.y = q8(*(const float4*)(p + 8), *(const float4*)(p + 12));
  }
  *(ulonglong2*)(w2q + (size_t)r * DH + c * 16) = v;  // rows 10..15 = 0
}

// ------------------------------ fused MLP -----------------------------------

__global__ __launch_bounds__(512, 4)
void fused_mlp(const float* __restrict__ x,
               const unsigned char* __restrict__ w1qb,
               const unsigned char* __restrict__ w2q,
               float* __restrict__ out) {
  __shared__ unsigned char A[NKS * MROWS * 64];   // 52 KB x-panel, read-only
  __shared__ unsigned char H[MROWS * CHUNK];      // 16 KB

  const int tid = threadIdx.x;
  const int lane = tid & 63;
  const int w  = tid >> 6;          // wave 0..7 -> dh slice w*32 of the chunk
  const int l31 = lane & 31;
  const int hi  = lane >> 5;
  const long row0 = (long)blockIdx.x * MROWS;

  // ---- prologue: quantize 64 x-rows into the LDS panel ----
  for (int it = 0; it < 7; ++it) {
    int idx = tid + it * 512;                     // 13*64*4 = 3328 writes
    if (idx < NKS * 256) {
      int ks = idx >> 8, rem = idx & 255, row = rem >> 2, q = rem & 3;
      int kA = ks * 64 + (q & 1) * 32 + (q >> 1) * 8;
      int kB = kA + 16;
      const float* xr = x + (row0 + row) * DIN;
      unsigned long long va = 0ull, vb = 0ull;
      if (kA < DIN) va = q8(*(const float4*)(xr + kA), *(const float4*)(xr + kA + 4));
      if (kB < DIN) vb = q8(*(const float4*)(xr + kB), *(const float4*)(xr + kB + 4));
      ulonglong2 v; v.x = va; v.y = vb;
      int slot = q ^ ((row >> 2) & 3);            // conflict-free involution
      *(ulonglong2*)&A[ks * 4096 + row * 64 + slot * 16] = v;
    }
  }
  __syncthreads();   // panel ready

  // loop-invariant offsets
  const int br0 = l31, br1 = l31 + 32;                      // x batch rows
#define SOFF(r_, g_) ((r_) * 64 + ((((g_) ^ (((r_) >> 2) & 3))) << 4))
  const unsigned char* aXlo0 = &A[SOFF(br0, 2 * hi)];
  const unsigned char* aXhi0 = &A[SOFF(br0, 2 * hi + 1)];
  const unsigned char* aXlo1 = &A[SOFF(br1, 2 * hi)];
  const unsigned char* aXhi1 = &A[SOFF(br1, 2 * hi + 1)];
#undef SOFF
  const int wh = w & 3, kh = w >> 2;                        // fc2: row quad, k-half
  const int r2 = wh * 16 + (lane & 15);                     // fc2 batch row
  const int x2 = (lane & 15) << 1;
  const int dh0 = w * 32 + 4 * hi;                          // H-write dh base
  const unsigned char* w2p0 = w2q + (size_t)(lane & 15) * DH + kh * 128 +
                              (lane >> 4) * 8;
  const unsigned char* wptr = w1qb + w * 2048 + (size_t)lane * 16;

  // phase rotation: waves 4..7 start the chunk at K-tile 7 (SIMD-mate of w<4)
  const int start = (w >> 2) & 1 ? 7 : 0;

  ulonglong2 wb_[2];
  ulonglong2 wbn_[2];
  wb_[0] = *(const ulonglong2*)(wptr + ((size_t)start << 14));
  wb_[1] = *(const ulonglong2*)(wptr + ((size_t)start << 14) + 1024);

  f32x4 acc2 = {0.f, 0.f, 0.f, 0.f};

  // inner 13-loop with compile-time rotation START_
#define INNER13(START_)                                                        \
  _Pragma("unroll")                                                            \
  for (int ks = 0; ks < NKS; ++ks) {                                           \
    const int kse = (ks + (START_)) % NKS;                                     \
    if (ks < NKS - 1) {                                                        \
      const int ksn = (kse + 1) % NKS;                                         \
      const unsigned char* np = wptr + ((size_t)ksn << 14);                    \
      wbn_[0] = *(const ulonglong2*)(np);                                      \
      wbn_[1] = *(const ulonglong2*)(np + 1024);                               \
    } else if (nch < NCH - 1) {                                                \
      const unsigned char* np = wptr + ((size_t)(NKS + (START_)) << 14);       \
      wbn_[0] = *(const ulonglong2*)(np);                                      \
      wbn_[1] = *(const ulonglong2*)(np + 1024);                               \
    }                                                                          \
    ulonglong2 B0lo = *(const ulonglong2*)(aXlo0 + kse * 4096);                \
    ulonglong2 B0hi = *(const ulonglong2*)(aXhi0 + kse * 4096);                \
    ulonglong2 B1lo = *(const ulonglong2*)(aXlo1 + kse * 4096);                \
    ulonglong2 B1hi = *(const ulonglong2*)(aXhi1 + kse * 4096);                \
    const ulonglong2 Alo = wb_[0];                                             \
    const ulonglong2 Ahi = wb_[1];                                             \
    __builtin_amdgcn_s_setprio(1);                                             \
    c0 = __builtin_amdgcn_mfma_f32_32x32x16_fp8_fp8((long)Alo.x, (long)B0lo.x, c0, 0, 0, 0); \
    c1 = __builtin_amdgcn_mfma_f32_32x32x16_fp8_fp8((long)Alo.x, (long)B1lo.x, c1, 0, 0, 0); \
    c0 = __builtin_amdgcn_mfma_f32_32x32x16_fp8_fp8((long)Alo.y, (long)B0lo.y, c0, 0, 0, 0); \
    c1 = __builtin_amdgcn_mfma_f32_32x32x16_fp8_fp8((long)Alo.y, (long)B1lo.y, c1, 0, 0, 0); \
    c0 = __builtin_amdgcn_mfma_f32_32x32x16_fp8_fp8((long)Ahi.x, (long)B0hi.x, c0, 0, 0, 0); \
    c1 = __builtin_amdgcn_mfma_f32_32x32x16_fp8_fp8((long)Ahi.x, (long)B1hi.x, c1, 0, 0, 0); \
    c0 = __builtin_amdgcn_mfma_f32_32x32x16_fp8_fp8((long)Ahi.y, (long)B0hi.y, c0, 0, 0, 0); \
    c1 = __builtin_amdgcn_mfma_f32_32x32x16_fp8_fp8((long)Ahi.y, (long)B1hi.y, c1, 0, 0, 0); \
    __builtin_amdgcn_s_setprio(0);                                             \
    wb_[0] = wbn_[0];                                                          \
    wb_[1] = wbn_[1];                                                          \
  }

#pragma unroll 1
  for (int nch = 0; nch < NCH; ++nch) {
    // hoist fc2 w2 fragments for this chunk (consumed after the inner loop)
    long b2v[4];
#pragma unroll
    for (int kk = 0; kk < 4; ++kk)
      b2v[kk] = *(const long long*)(w2p0 + nch * CHUNK + kk * 32);

    f32x16 c0 = zero16(), c1 = zero16();
    if (start) { INNER13(7) } else { INNER13(0) }
    wptr += (size_t)NKS << 14;

    // ---- relu + quantize -> H (dh-in-frag = (reg&3) + 8*(reg>>2) + 4*hi) ----
#define HWR(accv, rbv, dhb)                                                    \
    do {                                                                       \
      _Pragma("unroll") for (int qq = 0; qq < 4; ++qq) {                       \
        int dh_ = (dhb) + 8 * qq;                                              \
        unsigned wv = (unsigned)__builtin_amdgcn_cvt_pk_fp8_f32(               \
            fmaxf((accv)[4*qq+0], 0.f), fmaxf((accv)[4*qq+1], 0.f), 0, false); \
        wv = (unsigned)__builtin_amdgcn_cvt_pk_fp8_f32(                        \
            fmaxf((accv)[4*qq+2], 0.f), fmaxf((accv)[4*qq+3], 0.f), (int)wv, true); \
        int sp_ = (dh_ >> 2) ^ (((rbv) & 15) << 1);                            \
        *(unsigned int*)&H[(rbv) * CHUNK + sp_ * 4] = wv;                      \
      }                                                                        \
    } while (0)
    HWR(c0, br0, dh0);
    HWR(c1, br1, dh0);
#undef HWR
    asm volatile("s_waitcnt lgkmcnt(0)" ::: "memory");
    __builtin_amdgcn_s_barrier();
    asm volatile("" ::: "memory");
    // ---- fc2: 4 MFMAs (16x16x32), wave -> rows wh*16.., k-half kh*128 ----
#pragma unroll
    for (int kk = 0; kk < 4; ++kk) {
      int dhl = kh * 128 + kk * 32 + (lane >> 4) * 8;
      long a2 = *(const long long*)&H[r2 * CHUNK + (((dhl >> 2) ^ x2) << 2)];
      acc2 = __builtin_amdgcn_mfma_f32_16x16x32_fp8_fp8(a2, b2v[kk], acc2, 0, 0, 0);
    }
    asm volatile("s_waitcnt lgkmcnt(0)" ::: "memory");
    __builtin_amdgcn_s_barrier();   // H reads done before next chunk's writes
    asm volatile("" ::: "memory");
  }
#undef INNER13

  // ---- pair-reduce fc2 k-halves (waves wh and wh+4), store out[64][10] ----
  __syncthreads();
  float* red = (float*)&H[0];
  if (kh == 1) {
#pragma unroll
    for (int j = 0; j < 4; ++j)
      red[(wh * 16 + (lane >> 4) * 4 + j) * 16 + (lane & 15)] = acc2[j];
  }
  __syncthreads();
  if (kh == 0 && (lane & 15) < 10) {
#pragma unroll
    for (int j = 0; j < 4; ++j) {
      int rl = wh * 16 + (lane >> 4) * 4 + j;
      out[(row0 + rl) * 10 + (lane & 15)] = acc2[j] + red[rl * 16 + (lane & 15)];
    }
  }
}

extern "C" void kernel_launch(void* const* d_in, const int* in_sizes, int n_in,
                              void* d_out, int out_size, void* d_ws, size_t ws_size,
                              hipStream_t stream) {
  const float* x  = (const float*)d_in[0];
  const float* w1 = (const float*)d_in[1];
  const float* w2 = (const float*)d_in[2];
  float* out = (float*)d_out;

  unsigned char* w1qb = (unsigned char*)d_ws;             // blocked, 3.4MB
  unsigned char* w2q  = w1qb + (size_t)DH * KP;           // [16][4096]

  quant_w1_k<<<(DH * 52) / 256, 256, 0, stream>>>(w1, w1qb);
  quant_w2_k<<<16, 256, 0, stream>>>(w2, w2q);
  fused_mlp<<<32768 / MROWS, 512, 0, stream>>>(x, w1qb, w2q, out);
}